// Round 6
// baseline (168.751 us; speedup 1.0000x reference)
//
#include <hip/hip_runtime.h>

// MLPNodeLink: out[i,j] = relu(relu(relu([V1_i|V2_j]@W1+b1)@W2+b2)@W3+b3)
// h1[i,j] = relu(A[i] + B[j]), A=V1@W1[:128]+b1, B=V2@W1[128:]
// Round 6: BM 128->64 for 2 blocks/CU (4 waves/SIMD). acc[4][4]=64 regs,
// bf ping-pong per half-K-tile (32), af 16 -> ~120 unified regs, enforced by
// __launch_bounds__(512,4). Barrier-free K-loop, W2 frags direct from L2,
// fill of next block overlaps K-loop of current. Layer-3 fused in epilogue.

typedef short bf16x8 __attribute__((ext_vector_type(8)));
typedef float f32x4 __attribute__((ext_vector_type(4)));

#define NROW 512
#define FDIM 128
#define HDIM 512

__device__ __forceinline__ unsigned short f2bf(float x) {
  unsigned int u = __builtin_bit_cast(unsigned int, x);
  u += 0x7fffu + ((u >> 16) & 1u);
  return (unsigned short)(u >> 16);
}
__device__ __forceinline__ unsigned int pk2(float x, float y) {
  return (unsigned)f2bf(x) | ((unsigned)f2bf(y) << 16);
}

// ---- prep_ab: A[i][h] = V1[i]@W1[:128] + b1 ; B[j][h] = V2[j]@W1[128:] ----
__global__ __launch_bounds__(256) void prep_ab(
    const float* __restrict__ V1, const float* __restrict__ V2,
    const float* __restrict__ W1, const float* __restrict__ b1,
    float* __restrict__ Ap, float* __restrict__ Bp) {
  __shared__ float sv[4 * FDIM];
  const int b = blockIdx.x;
  const int t = threadIdx.x;
  const bool isB = b >= 128;
  const int r0 = (b & 127) * 4;
  const float* V = isB ? V2 : V1;
  const float* W = W1 + (isB ? FDIM * HDIM : 0);
  for (int idx = t; idx < 4 * FDIM; idx += 256) sv[idx] = V[r0 * FDIM + idx];
  __syncthreads();
  float s[4][2] = {};
  for (int k = 0; k < FDIM; ++k) {
    const float w0 = W[k * HDIM + t];
    const float w1 = W[k * HDIM + t + 256];
#pragma unroll
    for (int r = 0; r < 4; ++r) {
      const float v = sv[r * FDIM + k];
      s[r][0] += v * w0;
      s[r][1] += v * w1;
    }
  }
  float* O = isB ? Bp : Ap;
  const float bb0 = isB ? 0.f : b1[t];
  const float bb1 = isB ? 0.f : b1[t + 256];
#pragma unroll
  for (int r = 0; r < 4; ++r) {
    O[(r0 + r) * HDIM + t] = s[r][0] + bb0;
    O[(r0 + r) * HDIM + t + 256] = s[r][1] + bb1;
  }
}

// ---- prep_w2: bf16 W2^T tiled as [kt(8)][slot(8)][n(512)] 16B chunks ----
// Chunk o holds W2[kt*64 + slot*8 + e][n], e=0..7.
__global__ __launch_bounds__(256) void prep_w2(const float* __restrict__ W2,
                                               unsigned short* __restrict__ W2T) {
  const int o = blockIdx.x * 256 + threadIdx.x;  // 128*256 = 32768 chunks
  const int kt = o >> 12;
  const int s = (o >> 9) & 7;
  const int n = o & 511;
  const int kb = kt * 64 + s * 8;
  unsigned int u[4];
#pragma unroll
  for (int e2 = 0; e2 < 4; ++e2) {
    const unsigned short lo = f2bf(W2[(kb + 2 * e2) * HDIM + n]);
    const unsigned short hi = f2bf(W2[(kb + 2 * e2 + 1) * HDIM + n]);
    u[e2] = (unsigned)lo | ((unsigned)hi << 16);
  }
  *(uint4*)(W2T + (size_t)o * 8) = make_uint4(u[0], u[1], u[2], u[3]);
}

// ---- main: 64 pair-rows (one i, 64 j's) x full 512 cols per block ----
// 8 waves; each wave owns 64 rows x 64 cols (4 mt x 4 nt). K = 16 half-tiles
// of 32. LDS: sA = h1[64][512] bf16 chunk-XOR-swizzled (64KB) | sP (4KB).
__global__ __launch_bounds__(512, 4) void mlp_main(
    const float* __restrict__ Ap, const float* __restrict__ Bp,
    const unsigned short* __restrict__ W2T, const float* __restrict__ b2,
    const float* __restrict__ W3, const float* __restrict__ b3,
    float* __restrict__ out) {
  extern __shared__ char smem[];
  char* sA = smem;                      // 64 rows * 1024B; chunk c at (c^(row&7))*16
  float* sP = (float*)(smem + 65536);   // [8][64][2]

  const int tid = threadIdx.x;
  const int wave = tid >> 6;
  const int lane = tid & 63;
  const int lane15 = lane & 15;
  const int kgrp = lane >> 4;  // 0..3
  const int sw = lane15 & 7;   // row&7 for this lane's A-frag rows

  const int m0 = blockIdx.x * 64;
  const int i = m0 >> 9;
  const int j0 = m0 & 511;

  // ---- fill phase: h1 tile (64 rows x 512 k) -> sA ----
  {
    const int c = tid & 63;     // 16B chunk within row (8 k-elems)
    const int rsub = tid >> 6;  // 0..7
    const float4 a0 = *(const float4*)(Ap + i * HDIM + c * 8);
    const float4 a1 = *(const float4*)(Ap + i * HDIM + c * 8 + 4);
#pragma unroll
    for (int it = 0; it < 8; ++it) {
      const int row = it * 8 + rsub;
      const float4 g0 = *(const float4*)(Bp + (size_t)(j0 + row) * HDIM + c * 8);
      const float4 g1 = *(const float4*)(Bp + (size_t)(j0 + row) * HDIM + c * 8 + 4);
      const uint4 v = make_uint4(
          pk2(fmaxf(a0.x + g0.x, 0.f), fmaxf(a0.y + g0.y, 0.f)),
          pk2(fmaxf(a0.z + g0.z, 0.f), fmaxf(a0.w + g0.w, 0.f)),
          pk2(fmaxf(a1.x + g1.x, 0.f), fmaxf(a1.y + g1.y, 0.f)),
          pk2(fmaxf(a1.z + g1.z, 0.f), fmaxf(a1.w + g1.w, 0.f)));
      *(uint4*)(sA + row * 1024 + ((c ^ (row & 7)) << 4)) = v;
    }
  }
  __syncthreads();

  // ---- barrier-free K-loop: s = half-K-tile index 0..15 (K=32 each) ----
  f32x4 acc[4][4];
#pragma unroll
  for (int mt = 0; mt < 4; ++mt)
#pragma unroll
    for (int nt = 0; nt < 4; ++nt) acc[mt][nt] = (f32x4){0.f, 0.f, 0.f, 0.f};

  // W2T chunk = kt*4096 + (ks*4+kgrp)*512 + wave*64 + nt*16 + lane15
  //           = s*2048 + kgrp*512 + col   (s = kt*2+ks -> byte offset s<<15)
  const char* bbase = (const char*)W2T + (((kgrp << 9) + (wave << 6) + lane15) << 4);

  bf16x8 bf[2][4];  // [ping-pong][nt]
#pragma unroll
  for (int nt = 0; nt < 4; ++nt) bf[0][nt] = *(const bf16x8*)(bbase + (nt << 8));

#pragma unroll
  for (int s = 0; s < 16; ++s) {
    const int cur = s & 1;
    if (s < 15) {
      const char* p = bbase + ((s + 1) << 15);
#pragma unroll
      for (int nt = 0; nt < 4; ++nt) bf[cur ^ 1][nt] = *(const bf16x8*)(p + (nt << 8));
    }
    const int kt = s >> 1;
    const int ks = s & 1;
    const int csel = ((ks << 2) | kgrp) ^ sw;
    bf16x8 af[4];
#pragma unroll
    for (int mt = 0; mt < 4; ++mt) {
      const int row = mt * 16 + lane15;
      af[mt] = *(const bf16x8*)(sA + row * 1024 + (((kt << 3) | csel) << 4));
    }
#pragma unroll
    for (int nt = 0; nt < 4; ++nt)
#pragma unroll
      for (int mt = 0; mt < 4; ++mt)
        acc[mt][nt] =
            __builtin_amdgcn_mfma_f32_16x16x32_bf16(af[mt], bf[cur][nt], acc[mt][nt], 0, 0, 0);
  }

  // ---- epilogue: h2 = relu(acc + b2); layer-3 partials; reduce; store ----
  float w30[4], w31[4], bbv[4];
#pragma unroll
  for (int nt = 0; nt < 4; ++nt) {
    const int n = (wave << 6) + (nt << 4) + lane15;
    w30[nt] = W3[2 * n];
    w31[nt] = W3[2 * n + 1];
    bbv[nt] = b2[n];
  }
#pragma unroll
  for (int mt = 0; mt < 4; ++mt) {
    float p[4][2] = {};
#pragma unroll
    for (int nt = 0; nt < 4; ++nt)
#pragma unroll
      for (int q = 0; q < 4; ++q) {
        const float h = fmaxf(acc[mt][nt][q] + bbv[nt], 0.f);
        p[q][0] += h * w30[nt];
        p[q][1] += h * w31[nt];
      }
#pragma unroll
    for (int d = 1; d < 16; d <<= 1)
#pragma unroll
      for (int q = 0; q < 4; ++q) {
        p[q][0] += __shfl_xor(p[q][0], d, 64);
        p[q][1] += __shfl_xor(p[q][1], d, 64);
      }
    if (lane15 == 0) {
#pragma unroll
      for (int q = 0; q < 4; ++q) {
        const int r = mt * 16 + kgrp * 4 + q;
        sP[(wave * 64 + r) * 2 + 0] = p[q][0];
        sP[(wave * 64 + r) * 2 + 1] = p[q][1];
      }
    }
  }
  __syncthreads();
  if (tid < 128) {
    const int r = tid >> 1;
    const int c = tid & 1;
    float v = b3[c];
#pragma unroll
    for (int w = 0; w < 8; ++w) v += sP[(w * 64 + r) * 2 + c];
    out[((m0 + r) << 1) + c] = fmaxf(v, 0.f);
  }
}

extern "C" void kernel_launch(void* const* d_in, const int* in_sizes, int n_in,
                              void* d_out, int out_size, void* d_ws, size_t ws_size,
                              hipStream_t stream) {
  const float* V1 = (const float*)d_in[0];
  const float* V2 = (const float*)d_in[1];
  const float* W1 = (const float*)d_in[2];
  const float* b1 = (const float*)d_in[3];
  const float* W2 = (const float*)d_in[4];
  const float* b2 = (const float*)d_in[5];
  const float* W3 = (const float*)d_in[6];
  const float* b3 = (const float*)d_in[7];

  // ws layout: Ap (1MB f32) | Bp (1MB f32) | W2T (512KB bf16 tiled)
  float* Ap = (float*)d_ws;
  float* Bp = Ap + NROW * HDIM;
  unsigned short* W2T = (unsigned short*)(Bp + NROW * HDIM);

  const int smem_bytes = 65536 + 8 * 64 * 2 * 4;  // sA + sP = 69632
  (void)hipFuncSetAttribute((const void*)mlp_main,
                            hipFuncAttributeMaxDynamicSharedMemorySize, smem_bytes);

  prep_ab<<<256, 256, 0, stream>>>(V1, V2, W1, b1, Ap, Bp);
  prep_w2<<<128, 256, 0, stream>>>(W2, W2T);
  mlp_main<<<4096, 512, smem_bytes, stream>>>(Ap, Bp, W2T, b2, W3, b3, (float*)d_out);
}

// Round 7
// 163.146 us; speedup vs baseline: 1.0344x; 1.0344x over previous
//
#include <hip/hip_runtime.h>

// MLPNodeLink: out[i,j] = relu(relu(relu([V1_i|V2_j]@W1+b1)@W2+b2)@W3+b3)
// h1[i,j] = relu(A[i] + B[j]), A=V1@W1[:128]+b1, B=V2@W1[128:]
// Round 7: diagnosis = per-wave exposed ds_read latency (35% MFMA duty).
// Fixes: (1) software-pipelined K-loop, af/bf double-buffered 1 iter ahead;
// (2) 32x32x16 MFMA (better rate, half operand regs -> 4 waves/SIMD);
// (3) LDS transpose-reduce epilogue replaces 128-shuffle butterfly;
// (4) 4-bit XOR swizzle -> conflict-free af reads.

typedef short bf16x8 __attribute__((ext_vector_type(8)));
typedef float f32x16 __attribute__((ext_vector_type(16)));

#define NROW 512
#define FDIM 128
#define HDIM 512

__device__ __forceinline__ unsigned short f2bf(float x) {
  unsigned int u = __builtin_bit_cast(unsigned int, x);
  u += 0x7fffu + ((u >> 16) & 1u);
  return (unsigned short)(u >> 16);
}
__device__ __forceinline__ unsigned int pk2(float x, float y) {
  return (unsigned)f2bf(x) | ((unsigned)f2bf(y) << 16);
}

// ---- prep_ab: A[i][h] = V1[i]@W1[:128] + b1 ; B[j][h] = V2[j]@W1[128:] ----
__global__ __launch_bounds__(256) void prep_ab(
    const float* __restrict__ V1, const float* __restrict__ V2,
    const float* __restrict__ W1, const float* __restrict__ b1,
    float* __restrict__ Ap, float* __restrict__ Bp) {
  __shared__ float sv[4 * FDIM];
  const int b = blockIdx.x;
  const int t = threadIdx.x;
  const bool isB = b >= 128;
  const int r0 = (b & 127) * 4;
  const float* V = isB ? V2 : V1;
  const float* W = W1 + (isB ? FDIM * HDIM : 0);
  for (int idx = t; idx < 4 * FDIM; idx += 256) sv[idx] = V[r0 * FDIM + idx];
  __syncthreads();
  float s[4][2] = {};
  for (int k = 0; k < FDIM; ++k) {
    const float w0 = W[k * HDIM + t];
    const float w1 = W[k * HDIM + t + 256];
#pragma unroll
    for (int r = 0; r < 4; ++r) {
      const float v = sv[r * FDIM + k];
      s[r][0] += v * w0;
      s[r][1] += v * w1;
    }
  }
  float* O = isB ? Bp : Ap;
  const float bb0 = isB ? 0.f : b1[t];
  const float bb1 = isB ? 0.f : b1[t + 256];
#pragma unroll
  for (int r = 0; r < 4; ++r) {
    O[(r0 + r) * HDIM + t] = s[r][0] + bb0;
    O[(r0 + r) * HDIM + t + 256] = s[r][1] + bb1;
  }
}

// ---- prep_w2: bf16 W2^T as [kc=k/8 (64)][n (512)] 16B chunks ----
// Chunk o = kc*512+n holds W2[kc*8+e][n], e=0..7. A B-frag load (lanes 0..31
// consecutive n) reads 512B contiguous per half-wave.
__global__ __launch_bounds__(256) void prep_w2(const float* __restrict__ W2,
                                               unsigned short* __restrict__ W2T) {
  const int o = blockIdx.x * 256 + threadIdx.x;  // 128*256 = 32768 chunks
  const int kc = o >> 9;
  const int n = o & 511;
  unsigned int u[4];
#pragma unroll
  for (int e2 = 0; e2 < 4; ++e2) {
    const unsigned short lo = f2bf(W2[(kc * 8 + 2 * e2) * HDIM + n]);
    const unsigned short hi = f2bf(W2[(kc * 8 + 2 * e2 + 1) * HDIM + n]);
    u[e2] = (unsigned)lo | ((unsigned)hi << 16);
  }
  *(uint4*)(W2T + (size_t)o * 8) = make_uint4(u[0], u[1], u[2], u[3]);
}

// ---- main: 64 pair-rows x 512 cols per block; 8 waves, wave = 64x64 tile
// as 2x2 frags of 32x32. K pipelined in 32 steps of 16, af/bf dbuf 1 ahead.
// LDS: sA = h1[64][1024B], chunk c at (c^(row&15))*16 (64KB), reused by the
// epilogue as a [32][256][2] f32 transpose-reduce buffer.
__global__ __launch_bounds__(512, 4) void mlp_main(
    const float* __restrict__ Ap, const float* __restrict__ Bp,
    const unsigned short* __restrict__ W2T, const float* __restrict__ b2,
    const float* __restrict__ W3, const float* __restrict__ b3,
    float* __restrict__ out) {
  extern __shared__ char smem[];
  char* sA = smem;  // 64 KB

  const int tid = threadIdx.x;
  const int wave = tid >> 6;
  const int lane = tid & 63;
  const int cl = lane & 31;   // frag row/col index
  const int hi = lane >> 5;   // k-octet select
  const int r15 = lane & 15;  // row&15 for this lane's af rows (both mt)

  const int m0 = blockIdx.x * 64;
  const int i = m0 >> 9;
  const int j0 = m0 & 511;

  // ---- fill: h1 tile (64 rows x 512 k) -> sA, 4-bit XOR swizzle ----
  {
    const int c = tid & 63;     // 16B chunk (8 k-elems)
    const int rsub = tid >> 6;  // 0..7
    const float4 a0 = *(const float4*)(Ap + i * HDIM + c * 8);
    const float4 a1 = *(const float4*)(Ap + i * HDIM + c * 8 + 4);
#pragma unroll
    for (int it = 0; it < 8; ++it) {
      const int row = it * 8 + rsub;
      const float4 g0 = *(const float4*)(Bp + (size_t)(j0 + row) * HDIM + c * 8);
      const float4 g1 = *(const float4*)(Bp + (size_t)(j0 + row) * HDIM + c * 8 + 4);
      const uint4 v = make_uint4(
          pk2(fmaxf(a0.x + g0.x, 0.f), fmaxf(a0.y + g0.y, 0.f)),
          pk2(fmaxf(a0.z + g0.z, 0.f), fmaxf(a0.w + g0.w, 0.f)),
          pk2(fmaxf(a1.x + g1.x, 0.f), fmaxf(a1.y + g1.y, 0.f)),
          pk2(fmaxf(a1.z + g1.z, 0.f), fmaxf(a1.w + g1.w, 0.f)));
      *(uint4*)(sA + row * 1024 + ((c ^ (row & 15)) << 4)) = v;
    }
  }
  __syncthreads();

  // ---- pipelined K-loop: s = K/16 step; af from sA, bf from L2 ----
  f32x16 acc[2][2];
#pragma unroll
  for (int mt = 0; mt < 2; ++mt)
#pragma unroll
    for (int nt = 0; nt < 2; ++nt)
#pragma unroll
      for (int q = 0; q < 16; ++q) acc[mt][nt][q] = 0.f;

  const char* abase0 = sA + cl * 1024;  // mt=1 at +32768
  // B chunk o = (2s+hi)*512 + wave*64 + nt*32 + cl; byte = o*16
  const char* bbase = (const char*)W2T + (((wave << 6) + cl) << 4) + (hi << 13);

  bf16x8 af[2][2], bfr[2][2];
  {
    const int off = (hi ^ r15) << 4;  // s=0
    af[0][0] = *(const bf16x8*)(abase0 + off);
    af[0][1] = *(const bf16x8*)(abase0 + 32768 + off);
    bfr[0][0] = *(const bf16x8*)(bbase);
    bfr[0][1] = *(const bf16x8*)(bbase + (1 << 9));
  }
#pragma unroll
  for (int s = 0; s < 32; ++s) {
    const int cur = s & 1;
    const int nxt = cur ^ 1;
    if (s < 31) {
      const int off = ((((s + 1) << 1) | hi) ^ r15) << 4;
      af[nxt][0] = *(const bf16x8*)(abase0 + off);
      af[nxt][1] = *(const bf16x8*)(abase0 + 32768 + off);
      const char* bp = bbase + ((size_t)(s + 1) << 14);
      bfr[nxt][0] = *(const bf16x8*)(bp);
      bfr[nxt][1] = *(const bf16x8*)(bp + (1 << 9));
    }
    __builtin_amdgcn_s_setprio(1);
#pragma unroll
    for (int nt = 0; nt < 2; ++nt)
#pragma unroll
      for (int mt = 0; mt < 2; ++mt)
        acc[mt][nt] = __builtin_amdgcn_mfma_f32_32x32x16_bf16(af[cur][mt], bfr[cur][nt],
                                                              acc[mt][nt], 0, 0, 0);
    __builtin_amdgcn_s_setprio(0);
  }

  __syncthreads();  // sA reads done; buffer reused below

  // ---- epilogue: h2=relu(acc+b2); layer-3 partials -> LDS transpose-reduce
  float w30[2], w31[2], bb[2];
#pragma unroll
  for (int nt = 0; nt < 2; ++nt) {
    const int n = (wave << 6) + (nt << 5) + cl;
    w30[nt] = W3[2 * n];
    w31[nt] = W3[2 * n + 1];
    bb[nt] = b2[n];
  }
  const float bb3_0 = b3[0], bb3_1 = b3[1];

  for (int mt = 0; mt < 2; ++mt) {
    // write per-lane (p0,p1) partials: [r:32][slot:256=wave*32+cl][c:2] f32
#pragma unroll
    for (int reg = 0; reg < 16; ++reg) {
      const float h0 = fmaxf(acc[mt][0][reg] + bb[0], 0.f);
      const float h1 = fmaxf(acc[mt][1][reg] + bb[1], 0.f);
      const float p0 = h0 * w30[0] + h1 * w30[1];
      const float p1 = h0 * w31[0] + h1 * w31[1];
      const int r = (reg & 3) + ((reg >> 2) << 3) + (hi << 2);
      *(float2*)(smem + r * 2048 + (((wave << 5) + cl) << 3)) = make_float2(p0, p1);
    }
    __syncthreads();
    // reduce 256 slots -> out rows m0 + mt*32 + r
    {
      const int r = tid >> 4;    // 0..31
      const int sub = tid & 15;  // 16 threads per row
      float s0 = 0.f, s1 = 0.f;
#pragma unroll
      for (int k = 0; k < 16; ++k) {
        const int kk = (k + sub) & 15;  // stagger -> conflict-free
        const float2 v = *(const float2*)(smem + r * 2048 + (((sub << 4) + kk) << 3));
        s0 += v.x;
        s1 += v.y;
      }
#pragma unroll
      for (int d = 1; d < 16; d <<= 1) {
        s0 += __shfl_xor(s0, d, 64);
        s1 += __shfl_xor(s1, d, 64);
      }
      if (sub == 0) {
        const int rg = m0 + (mt << 5) + r;
        *(float2*)(out + rg * 2) = make_float2(fmaxf(s0 + bb3_0, 0.f), fmaxf(s1 + bb3_1, 0.f));
      }
    }
    __syncthreads();
  }
}

extern "C" void kernel_launch(void* const* d_in, const int* in_sizes, int n_in,
                              void* d_out, int out_size, void* d_ws, size_t ws_size,
                              hipStream_t stream) {
  const float* V1 = (const float*)d_in[0];
  const float* V2 = (const float*)d_in[1];
  const float* W1 = (const float*)d_in[2];
  const float* b1 = (const float*)d_in[3];
  const float* W2 = (const float*)d_in[4];
  const float* b2 = (const float*)d_in[5];
  const float* W3 = (const float*)d_in[6];
  const float* b3 = (const float*)d_in[7];

  // ws layout: Ap (1MB f32) | Bp (1MB f32) | W2T (512KB bf16 tiled)
  float* Ap = (float*)d_ws;
  float* Bp = Ap + NROW * HDIM;
  unsigned short* W2T = (unsigned short*)(Bp + NROW * HDIM);

  const int smem_bytes = 65536;
  (void)hipFuncSetAttribute((const void*)mlp_main,
                            hipFuncAttributeMaxDynamicSharedMemorySize, smem_bytes);

  prep_ab<<<256, 256, 0, stream>>>(V1, V2, W1, b1, Ap, Bp);
  prep_w2<<<128, 256, 0, stream>>>(W2, W2T);
  mlp_main<<<4096, 512, smem_bytes, stream>>>(Ap, Bp, W2T, b2, W3, b3, (float*)d_out);
}

// Round 9
// 157.727 us; speedup vs baseline: 1.0699x; 1.0344x over previous
//
#include <hip/hip_runtime.h>

// MLPNodeLink: out[i,j] = relu(relu(relu([V1_i|V2_j]@W1+b1)@W2+b2)@W3+b3)
// h1[i,j] = relu(A[i] + B[j]), A=V1@W1[:128]+b1, B=V2@W1[128:]
// Round 9: round 8 with the compile fix — pk2 via inline-asm
// v_cvt_pk_bf16_f32 (no builtin on gfx950; __hip_bfloat162 not bit_castable).

typedef short bf16x8 __attribute__((ext_vector_type(8)));
typedef float f32x16 __attribute__((ext_vector_type(16)));

#define NROW 512
#define FDIM 128
#define HDIM 512

__device__ __forceinline__ unsigned int pk2(float x, float y) {
  unsigned int r;
  asm("v_cvt_pk_bf16_f32 %0, %1, %2" : "=v"(r) : "v"(x), "v"(y));
  return r;
}

// ---- prep_ab: A[i][h] = V1[i]@W1[:128] + b1 ; B[j][h] = V2[j]@W1[128:] ----
__global__ __launch_bounds__(256) void prep_ab(
    const float* __restrict__ V1, const float* __restrict__ V2,
    const float* __restrict__ W1, const float* __restrict__ b1,
    float* __restrict__ Ap, float* __restrict__ Bp) {
  __shared__ float sv[4 * FDIM];
  const int b = blockIdx.x;
  const int t = threadIdx.x;
  const bool isB = b >= 128;
  const int r0 = (b & 127) * 4;
  const float* V = isB ? V2 : V1;
  const float* W = W1 + (isB ? FDIM * HDIM : 0);
  for (int idx = t; idx < 4 * FDIM; idx += 256) sv[idx] = V[r0 * FDIM + idx];
  __syncthreads();
  float s[4][2] = {};
  for (int k = 0; k < FDIM; ++k) {
    const float w0 = W[k * HDIM + t];
    const float w1 = W[k * HDIM + t + 256];
#pragma unroll
    for (int r = 0; r < 4; ++r) {
      const float v = sv[r * FDIM + k];
      s[r][0] += v * w0;
      s[r][1] += v * w1;
    }
  }
  float* O = isB ? Bp : Ap;
  const float bb0 = isB ? 0.f : b1[t];
  const float bb1 = isB ? 0.f : b1[t + 256];
#pragma unroll
  for (int r = 0; r < 4; ++r) {
    O[(r0 + r) * HDIM + t] = s[r][0] + bb0;
    O[(r0 + r) * HDIM + t + 256] = s[r][1] + bb1;
  }
}

// ---- prep_w2: bf16 W2^T as [kc=k/8 (64)][n (512)] 16B chunks ----
__global__ __launch_bounds__(256) void prep_w2(const float* __restrict__ W2,
                                               unsigned short* __restrict__ W2T) {
  const int o = blockIdx.x * 256 + threadIdx.x;  // 128*256 = 32768 chunks
  const int kc = o >> 9;
  const int n = o & 511;
  unsigned int u[4];
#pragma unroll
  for (int e2 = 0; e2 < 4; ++e2)
    u[e2] = pk2(W2[(kc * 8 + 2 * e2) * HDIM + n], W2[(kc * 8 + 2 * e2 + 1) * HDIM + n]);
  *(uint4*)(W2T + (size_t)o * 8) = make_uint4(u[0], u[1], u[2], u[3]);
}

// ---- main: 64 pair-rows x 512 cols per block; 8 waves, wave = 64x64 tile
// as 2x2 frags of 32x32. K pipelined in 32 steps of 16, af/bf dbuf 1 ahead.
__global__ __launch_bounds__(512, 4) void mlp_main(
    const float* __restrict__ Ap, const float* __restrict__ Bp,
    const unsigned short* __restrict__ W2T, const float* __restrict__ b2,
    const float* __restrict__ W3, const float* __restrict__ b3,
    float* __restrict__ out) {
  extern __shared__ char smem[];
  char* sA = smem;  // 64 KB; epilogue reuses as [16 rowpair][256 slot][16B]

  const int tid = threadIdx.x;
  const int wave = tid >> 6;
  const int lane = tid & 63;
  const int cl = lane & 31;   // frag row/col index
  const int hi = lane >> 5;   // k-octet select
  const int r15 = lane & 15;  // row&15 for this lane's af rows (both mt)

  const int m0 = blockIdx.x * 64;
  const int i = m0 >> 9;
  const int j0 = m0 & 511;

  // ---- fill: h1 tile (64 rows x 512 k) -> sA, 4-bit XOR swizzle ----
  {
    const int c = tid & 63;     // 16B chunk (8 k-elems)
    const int rsub = tid >> 6;  // 0..7
    const float4 a0 = *(const float4*)(Ap + i * HDIM + c * 8);
    const float4 a1 = *(const float4*)(Ap + i * HDIM + c * 8 + 4);
#pragma unroll
    for (int it = 0; it < 8; ++it) {
      const int row = it * 8 + rsub;
      const float4 g0 = *(const float4*)(Bp + (size_t)(j0 + row) * HDIM + c * 8);
      const float4 g1 = *(const float4*)(Bp + (size_t)(j0 + row) * HDIM + c * 8 + 4);
      const uint4 v = make_uint4(
          pk2(fmaxf(a0.x + g0.x, 0.f), fmaxf(a0.y + g0.y, 0.f)),
          pk2(fmaxf(a0.z + g0.z, 0.f), fmaxf(a0.w + g0.w, 0.f)),
          pk2(fmaxf(a1.x + g1.x, 0.f), fmaxf(a1.y + g1.y, 0.f)),
          pk2(fmaxf(a1.z + g1.z, 0.f), fmaxf(a1.w + g1.w, 0.f)));
      *(uint4*)(sA + row * 1024 + ((c ^ (row & 15)) << 4)) = v;
    }
  }

  // hoisted epilogue weights (latency hidden under K-loop)
  float w30[2], w31[2], bb[2];
#pragma unroll
  for (int nt = 0; nt < 2; ++nt) {
    const int n = (wave << 6) + (nt << 5) + cl;
    w30[nt] = W3[2 * n];
    w31[nt] = W3[2 * n + 1];
    bb[nt] = b2[n];
  }
  const float bb3_0 = b3[0], bb3_1 = b3[1];

  __syncthreads();

  // ---- pipelined K-loop: s = K/16 step; af from sA, bf from L2 ----
  f32x16 acc[2][2];
#pragma unroll
  for (int mt = 0; mt < 2; ++mt)
#pragma unroll
    for (int nt = 0; nt < 2; ++nt)
#pragma unroll
      for (int q = 0; q < 16; ++q) acc[mt][nt][q] = 0.f;

  const char* abase0 = sA + cl * 1024;  // mt=1 at +32768
  const char* bbase = (const char*)W2T + (((wave << 6) + cl) << 4) + (hi << 13);

  bf16x8 af[2][2], bfr[2][2];
  {
    const int off = (hi ^ r15) << 4;  // s=0
    af[0][0] = *(const bf16x8*)(abase0 + off);
    af[0][1] = *(const bf16x8*)(abase0 + 32768 + off);
    bfr[0][0] = *(const bf16x8*)(bbase);
    bfr[0][1] = *(const bf16x8*)(bbase + (1 << 9));
  }
#pragma unroll
  for (int s = 0; s < 32; ++s) {
    const int cur = s & 1;
    const int nxt = cur ^ 1;
    if (s < 31) {
      const int off = ((((s + 1) << 1) | hi) ^ r15) << 4;
      af[nxt][0] = *(const bf16x8*)(abase0 + off);
      af[nxt][1] = *(const bf16x8*)(abase0 + 32768 + off);
      const char* bp = bbase + ((size_t)(s + 1) << 14);
      bfr[nxt][0] = *(const bf16x8*)(bp);
      bfr[nxt][1] = *(const bf16x8*)(bp + (1 << 9));
    }
    __builtin_amdgcn_s_setprio(1);
#pragma unroll
    for (int nt = 0; nt < 2; ++nt)
#pragma unroll
      for (int mt = 0; mt < 2; ++mt)
        acc[mt][nt] = __builtin_amdgcn_mfma_f32_32x32x16_bf16(af[cur][mt], bfr[cur][nt],
                                                              acc[mt][nt], 0, 0, 0);
    __builtin_amdgcn_s_setprio(0);
  }

  __syncthreads();  // sA reads done; buffer reused below

  // ---- epilogue: h2=relu(acc+b2); p=(h2 row-slice)@W3; LDS reduce ----
  // Buffer layout per mt round: [rowpair rp:16][slot:256=wave*32+cl][p0,p1,p0',p1']
  for (int mt = 0; mt < 2; ++mt) {
#pragma unroll
    for (int rp = 0; rp < 8; ++rp) {
      const int ra = 2 * rp;  // regs ra, ra+1 -> adjacent rows
      const float h0a = fmaxf(acc[mt][0][ra] + bb[0], 0.f);
      const float h1a = fmaxf(acc[mt][1][ra] + bb[1], 0.f);
      const float h0b = fmaxf(acc[mt][0][ra + 1] + bb[0], 0.f);
      const float h1b = fmaxf(acc[mt][1][ra + 1] + bb[1], 0.f);
      const float4 v = make_float4(h0a * w30[0] + h1a * w30[1], h0a * w31[0] + h1a * w31[1],
                                   h0b * w30[0] + h1b * w30[1], h0b * w31[0] + h1b * w31[1]);
      // row of reg ra: (ra&3) + 8*(ra>>2) + 4*hi ; rp index = row>>1
      const int rpi = ((ra & 3) + 8 * (ra >> 2) + 4 * hi) >> 1;
      *(float4*)(smem + rpi * 4096 + (((wave << 5) + cl) << 4)) = v;
    }
    __syncthreads();
    if (tid < 256) {
      const int rpi = tid >> 4;   // 0..15
      const int sub = tid & 15;   // 16 threads per rowpair
      float4 s = make_float4(0.f, 0.f, 0.f, 0.f);
#pragma unroll
      for (int k = 0; k < 16; ++k) {
        const float4 v = *(const float4*)(smem + rpi * 4096 + ((sub + (k << 4)) << 4));
        s.x += v.x; s.y += v.y; s.z += v.z; s.w += v.w;
      }
#pragma unroll
      for (int d = 1; d < 16; d <<= 1) {
        s.x += __shfl_xor(s.x, d, 64);
        s.y += __shfl_xor(s.y, d, 64);
        s.z += __shfl_xor(s.z, d, 64);
        s.w += __shfl_xor(s.w, d, 64);
      }
      if (sub == 0) {
        const int rg = m0 + (mt << 5) + (rpi << 1);
        *(float4*)(out + rg * 2) =
            make_float4(fmaxf(s.x + bb3_0, 0.f), fmaxf(s.y + bb3_1, 0.f),
                        fmaxf(s.z + bb3_0, 0.f), fmaxf(s.w + bb3_1, 0.f));
      }
    }
    __syncthreads();
  }
}

extern "C" void kernel_launch(void* const* d_in, const int* in_sizes, int n_in,
                              void* d_out, int out_size, void* d_ws, size_t ws_size,
                              hipStream_t stream) {
  const float* V1 = (const float*)d_in[0];
  const float* V2 = (const float*)d_in[1];
  const float* W1 = (const float*)d_in[2];
  const float* b1 = (const float*)d_in[3];
  const float* W2 = (const float*)d_in[4];
  const float* b2 = (const float*)d_in[5];
  const float* W3 = (const float*)d_in[6];
  const float* b3 = (const float*)d_in[7];

  // ws layout: Ap (1MB f32) | Bp (1MB f32) | W2T (512KB bf16 tiled)
  float* Ap = (float*)d_ws;
  float* Bp = Ap + NROW * HDIM;
  unsigned short* W2T = (unsigned short*)(Bp + NROW * HDIM);

  const int smem_bytes = 65536;
  (void)hipFuncSetAttribute((const void*)mlp_main,
                            hipFuncAttributeMaxDynamicSharedMemorySize, smem_bytes);

  prep_ab<<<256, 256, 0, stream>>>(V1, V2, W1, b1, Ap, Bp);
  prep_w2<<<128, 256, 0, stream>>>(W2, W2T);
  mlp_main<<<4096, 512, smem_bytes, stream>>>(Ap, Bp, W2T, b2, W3, b3, (float*)d_out);
}

// Round 10
// 152.546 us; speedup vs baseline: 1.1062x; 1.0340x over previous
//
#include <hip/hip_runtime.h>

// MLPNodeLink: out[i,j] = relu(relu(relu([V1_i|V2_j]@W1+b1)@W2+b2)@W3+b3)
// h1[i,j] = relu(A[i] + B[j]), A=V1@W1[:128]+b1, B=V2@W1[128:]
// Round 10: BM=128 with per-wave M-replication (wave = 128x64 via 4mt x 2nt
// 32x32 frags). Halves W2 L2 traffic (each B-frag feeds 8 MFMAs) -> K-loop
// MFMA-bound. bfr prefetch 2-deep (3-slot), af 1-deep. 1 block/CU, 128KB sA.

typedef short bf16x8 __attribute__((ext_vector_type(8)));
typedef float f32x16 __attribute__((ext_vector_type(16)));

#define NROW 512
#define FDIM 128
#define HDIM 512

__device__ __forceinline__ unsigned int pk2(float x, float y) {
  unsigned int r;
  asm("v_cvt_pk_bf16_f32 %0, %1, %2" : "=v"(r) : "v"(x), "v"(y));
  return r;
}

// ---- prep_ab: A[i][h] = V1[i]@W1[:128] + b1 ; B[j][h] = V2[j]@W1[128:] ----
__global__ __launch_bounds__(256) void prep_ab(
    const float* __restrict__ V1, const float* __restrict__ V2,
    const float* __restrict__ W1, const float* __restrict__ b1,
    float* __restrict__ Ap, float* __restrict__ Bp) {
  __shared__ float sv[4 * FDIM];
  const int b = blockIdx.x;
  const int t = threadIdx.x;
  const bool isB = b >= 128;
  const int r0 = (b & 127) * 4;
  const float* V = isB ? V2 : V1;
  const float* W = W1 + (isB ? FDIM * HDIM : 0);
  for (int idx = t; idx < 4 * FDIM; idx += 256) sv[idx] = V[r0 * FDIM + idx];
  __syncthreads();
  float s[4][2] = {};
  for (int k = 0; k < FDIM; ++k) {
    const float w0 = W[k * HDIM + t];
    const float w1 = W[k * HDIM + t + 256];
#pragma unroll
    for (int r = 0; r < 4; ++r) {
      const float v = sv[r * FDIM + k];
      s[r][0] += v * w0;
      s[r][1] += v * w1;
    }
  }
  float* O = isB ? Bp : Ap;
  const float bb0 = isB ? 0.f : b1[t];
  const float bb1 = isB ? 0.f : b1[t + 256];
#pragma unroll
  for (int r = 0; r < 4; ++r) {
    O[(r0 + r) * HDIM + t] = s[r][0] + bb0;
    O[(r0 + r) * HDIM + t + 256] = s[r][1] + bb1;
  }
}

// ---- prep_w2: bf16 W2^T as [kc=k/8 (64)][n (512)] 16B chunks ----
__global__ __launch_bounds__(256) void prep_w2(const float* __restrict__ W2,
                                               unsigned short* __restrict__ W2T) {
  const int o = blockIdx.x * 256 + threadIdx.x;  // 128*256 = 32768 chunks
  const int kc = o >> 9;
  const int n = o & 511;
  unsigned int u[4];
#pragma unroll
  for (int e2 = 0; e2 < 4; ++e2)
    u[e2] = pk2(W2[(kc * 8 + 2 * e2) * HDIM + n], W2[(kc * 8 + 2 * e2 + 1) * HDIM + n]);
  *(uint4*)(W2T + (size_t)o * 8) = make_uint4(u[0], u[1], u[2], u[3]);
}

// ---- main: 128 pair-rows x 512 cols per block; 8 waves; wave = 128x64 tile
// as 4 mt x 2 nt frags of 32x32. K: 32 steps of 16; af 1-deep, bfr 2-deep.
__global__ __launch_bounds__(512, 2) void mlp_main(
    const float* __restrict__ Ap, const float* __restrict__ Bp,
    const unsigned short* __restrict__ W2T, const float* __restrict__ b2,
    const float* __restrict__ W3, const float* __restrict__ b3,
    float* __restrict__ out) {
  extern __shared__ char smem[];
  char* sA = smem;  // 128 rows * 1024B = 128KB; first 64KB reused by epilogue

  const int tid = threadIdx.x;
  const int wave = tid >> 6;
  const int lane = tid & 63;
  const int cl = lane & 31;   // frag row/col index
  const int hi = lane >> 5;   // k-octet select
  const int r15 = lane & 15;  // row&15 for af rows (all mt: (mt*32+cl)&15 = cl&15)

  const int m0 = blockIdx.x * 128;
  const int i = m0 >> 9;
  const int j0 = m0 & 511;

  // ---- fill: h1 tile (128 rows x 512 k) -> sA, 4-bit XOR swizzle ----
  {
    const int c = tid & 63;     // 16B chunk (8 k-elems)
    const int rsub = tid >> 6;  // 0..7
    const float4 a0 = *(const float4*)(Ap + i * HDIM + c * 8);
    const float4 a1 = *(const float4*)(Ap + i * HDIM + c * 8 + 4);
#pragma unroll
    for (int it = 0; it < 16; ++it) {
      const int row = it * 8 + rsub;
      const float4 g0 = *(const float4*)(Bp + (size_t)(j0 + row) * HDIM + c * 8);
      const float4 g1 = *(const float4*)(Bp + (size_t)(j0 + row) * HDIM + c * 8 + 4);
      const uint4 v = make_uint4(
          pk2(fmaxf(a0.x + g0.x, 0.f), fmaxf(a0.y + g0.y, 0.f)),
          pk2(fmaxf(a0.z + g0.z, 0.f), fmaxf(a0.w + g0.w, 0.f)),
          pk2(fmaxf(a1.x + g1.x, 0.f), fmaxf(a1.y + g1.y, 0.f)),
          pk2(fmaxf(a1.z + g1.z, 0.f), fmaxf(a1.w + g1.w, 0.f)));
      *(uint4*)(sA + row * 1024 + ((c ^ (row & 15)) << 4)) = v;
    }
  }

  // hoisted epilogue weights (latency hidden under K-loop)
  float w30[2], w31[2], bb[2];
#pragma unroll
  for (int nt = 0; nt < 2; ++nt) {
    const int n = (wave << 6) + (nt << 5) + cl;
    w30[nt] = W3[2 * n];
    w31[nt] = W3[2 * n + 1];
    bb[nt] = b2[n];
  }
  const float bb3_0 = b3[0], bb3_1 = b3[1];

  __syncthreads();

  // ---- pipelined K-loop: s = K/16 step; af from sA (1-deep), bfr from L2
  // (2-deep, 3-slot rotating; all indices compile-time via full unroll) ----
  f32x16 acc[4][2];
#pragma unroll
  for (int mt = 0; mt < 4; ++mt)
#pragma unroll
    for (int nt = 0; nt < 2; ++nt)
#pragma unroll
      for (int q = 0; q < 16; ++q) acc[mt][nt][q] = 0.f;

  const char* abase0 = sA + cl * 1024;  // mt at +mt*32768
  const char* bbase = (const char*)W2T + (((wave << 6) + cl) << 4) + (hi << 13);

  bf16x8 af[2][4], bfr[3][2];
  {
    const int off = (hi ^ r15) << 4;  // s=0
#pragma unroll
    for (int mt = 0; mt < 4; ++mt) af[0][mt] = *(const bf16x8*)(abase0 + mt * 32768 + off);
#pragma unroll
    for (int q = 0; q < 3; ++q) {
      const char* bp = bbase + ((size_t)q << 14);
      bfr[q][0] = *(const bf16x8*)(bp);
      bfr[q][1] = *(const bf16x8*)(bp + (1 << 9));
    }
  }
#pragma unroll
  for (int s = 0; s < 32; ++s) {
    const int cur = s & 1;
    if (s < 31) {
      const int off = ((((s + 1) << 1) | hi) ^ r15) << 4;
#pragma unroll
      for (int mt = 0; mt < 4; ++mt)
        af[cur ^ 1][mt] = *(const bf16x8*)(abase0 + mt * 32768 + off);
    }
    if (s < 30) {
      const char* bp = bbase + ((size_t)(s + 2) << 14);
      bfr[(s + 2) % 3][0] = *(const bf16x8*)(bp);
      bfr[(s + 2) % 3][1] = *(const bf16x8*)(bp + (1 << 9));
    }
    __builtin_amdgcn_s_setprio(1);
#pragma unroll
    for (int nt = 0; nt < 2; ++nt)
#pragma unroll
      for (int mt = 0; mt < 4; ++mt)
        acc[mt][nt] = __builtin_amdgcn_mfma_f32_32x32x16_bf16(af[cur][mt], bfr[s % 3][nt],
                                                              acc[mt][nt], 0, 0, 0);
    __builtin_amdgcn_s_setprio(0);
  }

  __syncthreads();  // sA reads done; buffer reused below

  // ---- epilogue: h2=relu(acc+b2); p=(h2 row-slice)@W3; LDS reduce ----
  // Per mt round: [rowpair rpi:16][slot:256=wave*32+cl][p0,p1,p0',p1'] (64KB)
#pragma unroll
  for (int mt = 0; mt < 4; ++mt) {
#pragma unroll
    for (int rp = 0; rp < 8; ++rp) {
      const int ra = 2 * rp;  // regs ra, ra+1 -> adjacent rows
      const float h0a = fmaxf(acc[mt][0][ra] + bb[0], 0.f);
      const float h1a = fmaxf(acc[mt][1][ra] + bb[1], 0.f);
      const float h0b = fmaxf(acc[mt][0][ra + 1] + bb[0], 0.f);
      const float h1b = fmaxf(acc[mt][1][ra + 1] + bb[1], 0.f);
      const float4 v = make_float4(h0a * w30[0] + h1a * w30[1], h0a * w31[0] + h1a * w31[1],
                                   h0b * w30[0] + h1b * w30[1], h0b * w31[0] + h1b * w31[1]);
      // row of reg ra: (ra&3) + 8*(ra>>2) + 4*hi ; rpi = row>>1
      const int rpi = ((ra & 3) + 8 * (ra >> 2) + 4 * hi) >> 1;
      *(float4*)(smem + rpi * 4096 + (((wave << 5) + cl) << 4)) = v;
    }
    __syncthreads();
    if (tid < 256) {
      const int rpi = tid >> 4;  // 0..15
      const int sub = tid & 15;  // 16 threads per rowpair
      float4 s = make_float4(0.f, 0.f, 0.f, 0.f);
#pragma unroll
      for (int k = 0; k < 16; ++k) {
        const float4 v = *(const float4*)(smem + rpi * 4096 + ((sub + (k << 4)) << 4));
        s.x += v.x; s.y += v.y; s.z += v.z; s.w += v.w;
      }
#pragma unroll
      for (int d = 1; d < 16; d <<= 1) {
        s.x += __shfl_xor(s.x, d, 64);
        s.y += __shfl_xor(s.y, d, 64);
        s.z += __shfl_xor(s.z, d, 64);
        s.w += __shfl_xor(s.w, d, 64);
      }
      if (sub == 0) {
        const int rg = m0 + (mt << 5) + (rpi << 1);
        *(float4*)(out + rg * 2) =
            make_float4(fmaxf(s.x + bb3_0, 0.f), fmaxf(s.y + bb3_1, 0.f),
                        fmaxf(s.z + bb3_0, 0.f), fmaxf(s.w + bb3_1, 0.f));
      }
    }
    __syncthreads();
  }
}

extern "C" void kernel_launch(void* const* d_in, const int* in_sizes, int n_in,
                              void* d_out, int out_size, void* d_ws, size_t ws_size,
                              hipStream_t stream) {
  const float* V1 = (const float*)d_in[0];
  const float* V2 = (const float*)d_in[1];
  const float* W1 = (const float*)d_in[2];
  const float* b1 = (const float*)d_in[3];
  const float* W2 = (const float*)d_in[4];
  const float* b2 = (const float*)d_in[5];
  const float* W3 = (const float*)d_in[6];
  const float* b3 = (const float*)d_in[7];

  // ws layout: Ap (1MB f32) | Bp (1MB f32) | W2T (512KB bf16 tiled)
  float* Ap = (float*)d_ws;
  float* Bp = Ap + NROW * HDIM;
  unsigned short* W2T = (unsigned short*)(Bp + NROW * HDIM);

  const int smem_bytes = 131072;
  (void)hipFuncSetAttribute((const void*)mlp_main,
                            hipFuncAttributeMaxDynamicSharedMemorySize, smem_bytes);

  prep_ab<<<256, 256, 0, stream>>>(V1, V2, W1, b1, Ap, Bp);
  prep_w2<<<128, 256, 0, stream>>>(W2, W2T);
  mlp_main<<<2048, 512, smem_bytes, stream>>>(Ap, Bp, W2T, b2, W3, b3, (float*)d_out);
}